// Round 4
// baseline (1399.893 us; speedup 1.0000x reference)
//
#include <hip/hip_runtime.h>
#include <string.h>

typedef __bf16 bf16x8 __attribute__((ext_vector_type(8)));
typedef float f32x4 __attribute__((ext_vector_type(4)));
typedef unsigned short u16;
typedef u16 u16x8 __attribute__((ext_vector_type(8)));

#define NB 16     // batch
#define CD 512    // channels
#define NN 4096   // hw
#define O3 1536   // 3*hidden

__device__ __forceinline__ u16 f2bf(float f) {
    union { float f; unsigned int u; } v; v.f = f;
    unsigned int r = v.u + 0x7fffu + ((v.u >> 16) & 1u);
    return (u16)(r >> 16);
}
__device__ __forceinline__ float bf2f(u16 s) {
    union { unsigned int u; float f; } v; v.u = ((unsigned int)s) << 16;
    return v.f;
}

__device__ __forceinline__ void gl2lds16(const u16* g, u16* l) {
    __builtin_amdgcn_global_load_lds(
        (const void __attribute__((address_space(1)))*)g,
        (void __attribute__((address_space(3)))*)l,
        16, 0, 0);
}

// ---------------- convert w_qkv fp32 -> bf16 (row-major [1536][512]) ----------
__global__ void k_convert(const float* __restrict__ in, u16* __restrict__ out, int n) {
    int i = blockIdx.x * 256 + threadIdx.x;
    if (i < n) out[i] = f2bf(in[i]);
}

// ---------------- transpose x[b][c][n] fp32 -> xt[b][n][c] bf16, 64x64 tiles --
__global__ __launch_bounds__(256) void k_transpose_x(const float* __restrict__ x,
                                                     u16* __restrict__ xt) {
    __shared__ float tile[64][65];
    const int b = blockIdx.y;
    const int ntile = blockIdx.x & 63;   // 4096/64
    const int ctile = blockIdx.x >> 6;   // 512/64
    const int t = threadIdx.x;
    const int r = t >> 2;                // 0..63 (row)
    const int q = t & 3;                 // 4 threads per row

    const float* xb = x + ((size_t)b * CD + ctile * 64 + r) * NN + ntile * 64;
#pragma unroll
    for (int j = 0; j < 4; ++j) {
        float4 v = *(const float4*)&xb[q * 16 + j * 4];
        tile[r][q * 16 + j * 4 + 0] = v.x;
        tile[r][q * 16 + j * 4 + 1] = v.y;
        tile[r][q * 16 + j * 4 + 2] = v.z;
        tile[r][q * 16 + j * 4 + 3] = v.w;
    }
    __syncthreads();
    u16* xtb = xt + ((size_t)b * NN + ntile * 64 + r) * CD + ctile * 64 + q * 16;
    u16x8 o0, o1;
#pragma unroll
    for (int j = 0; j < 8; ++j) {
        o0[j] = f2bf(tile[q * 16 + j][r]);
        o1[j] = f2bf(tile[q * 16 + 8 + j][r]);
    }
    *(u16x8*)&xtb[0] = o0;
    *(u16x8*)&xtb[8] = o1;
}

// =============================================================================
// 256x256 bf16 GEMM core — BK=32, 64 KiB LDS double-buffer, 2 BLOCKS/CU.
//
// Rationale (R4): R1-R3 showed the schedule is not the limiter (MfmaUtil stuck
// 32-34% across 3 schedule variants); the limiter is 1 block/CU residency.
// BK=32 halves LDS to 64 KiB -> 2 co-resident blocks fill each other's
// barrier/prologue/epilogue stalls. Each ds_read_b128 now covers a full MFMA
// K-step: 12 reads/wave/K-tile = 96 KB/CU reads + 32 KB writes ~ 1000 cyc
// < 1242 cyc MFMA -> LDS bandwidth off the critical path.
//
// Swizzle for 32-elem (64 B) rows: 4 slots of 16 B; slot ^= (row>>1)&3.
// Balanced: every bank receives exactly 32 B per wave-read (2-way = free).
// Both sides: pre-swizzled global source (linear gl2lds dest) + swizzled read.
// One barrier per K-tile; stages for kt+1 issue at top of kt; own-wave
// vmcnt(0) before the tile-end barrier (drain covered by the other block).
// =============================================================================

#define BAR() do { \
    asm volatile("" ::: "memory"); \
    __builtin_amdgcn_s_barrier(); \
    asm volatile("" ::: "memory"); \
} while (0)

__device__ __forceinline__ void gemm256_core(u16* __restrict__ smem,
                                             const u16* __restrict__ Abase,
                                             const u16* __restrict__ Bbase,
                                             f32x4 (&acc)[2][2][4][2]) {
    const int t = threadIdx.x;
    const int lane = t & 63;
    const int w = t >> 6;
    const int l15 = lane & 15, quad = lane >> 4;
    const int r0 = t >> 2;                           // staging row 0..127
    const int sg = ((t & 3) ^ ((r0 >> 1) & 3)) * 8;  // pre-swizzled src k-slot
    const int am = (w >> 2) * 64 + l15;              // A row base within half
    const int bn = (w & 3) * 32 + l15;               // B row base within half
    const int rsw = (quad ^ ((l15 >> 1) & 3)) << 3;  // swizzled k-slot on read

    auto ldsAt = [&](int s, int op, int half) -> u16* {
        return smem + (size_t)(((s * 2 + op) * 2 + half) * 4096);  // 128x32 each
    };
    auto stage = [&](int op, int half, int tau) {
        const u16* src = (op ? Bbase : Abase)
                         + (size_t)(half * 128 + r0) * CD + tau * 32 + sg;
        gl2lds16(src, ldsAt(tau & 1, op, half) + t * 8);
    };

    // prologue: tile 0 (4 x 8 KiB)
    stage(0, 0, 0); stage(0, 1, 0); stage(1, 0, 0); stage(1, 1, 0);
    asm volatile("s_waitcnt vmcnt(0)" ::: "memory");
    BAR();

    bf16x8 aa[4], bb0[2], bb1[2];
    for (int kt = 0; kt < 16; ++kt) {
        const int s = kt & 1;
        const u16* pa0 = ldsAt(s, 0, 0);
        const u16* pa1 = ldsAt(s, 0, 1);
        const u16* pb0 = ldsAt(s, 1, 0);
        const u16* pb1 = ldsAt(s, 1, 1);
#pragma unroll
        for (int mi = 0; mi < 4; ++mi)
            aa[mi] = *(const bf16x8*)&pa0[(am + mi * 16) * 32 + rsw];
#pragma unroll
        for (int ni = 0; ni < 2; ++ni) {
            bb0[ni] = *(const bf16x8*)&pb0[(bn + ni * 16) * 32 + rsw];
            bb1[ni] = *(const bf16x8*)&pb1[(bn + ni * 16) * 32 + rsw];
        }
        if (kt < 15) {
            stage(0, 0, kt + 1); stage(0, 1, kt + 1);
            stage(1, 0, kt + 1); stage(1, 1, kt + 1);
        }
        __builtin_amdgcn_s_setprio(1);
#pragma unroll
        for (int mi = 0; mi < 4; ++mi)
#pragma unroll
            for (int ni = 0; ni < 2; ++ni) {
                acc[0][0][mi][ni] = __builtin_amdgcn_mfma_f32_16x16x32_bf16(
                    aa[mi], bb0[ni], acc[0][0][mi][ni], 0, 0, 0);
                acc[0][1][mi][ni] = __builtin_amdgcn_mfma_f32_16x16x32_bf16(
                    aa[mi], bb1[ni], acc[0][1][mi][ni], 0, 0, 0);
            }
        __builtin_amdgcn_s_setprio(0);
#pragma unroll
        for (int mi = 0; mi < 4; ++mi)
            aa[mi] = *(const bf16x8*)&pa1[(am + mi * 16) * 32 + rsw];
        __builtin_amdgcn_s_setprio(1);
#pragma unroll
        for (int mi = 0; mi < 4; ++mi)
#pragma unroll
            for (int ni = 0; ni < 2; ++ni) {
                acc[1][0][mi][ni] = __builtin_amdgcn_mfma_f32_16x16x32_bf16(
                    aa[mi], bb0[ni], acc[1][0][mi][ni], 0, 0, 0);
                acc[1][1][mi][ni] = __builtin_amdgcn_mfma_f32_16x16x32_bf16(
                    aa[mi], bb1[ni], acc[1][1][mi][ni], 0, 0, 0);
            }
        __builtin_amdgcn_s_setprio(0);
        if (kt < 15) asm volatile("s_waitcnt vmcnt(0)" ::: "memory");
        BAR();
    }
}

// ---------------- GEMM1: qkv = Wqkv(1536x512) @ X_b(512x4096) -----------------
// m-tiles of 256 align with sections: mt 0-1 -> Q, 2-3 -> K, 4-5 -> V.
__global__ __launch_bounds__(512, 4) void k_gemm1(
        const u16* __restrict__ A, const u16* __restrict__ Bt,
        u16* __restrict__ qt, u16* __restrict__ kbuf, u16* __restrict__ vbuf) {
    __shared__ __align__(16) u16 smem[32768];   // 64 KiB loop double-buffer
    const int gid = blockIdx.x;                 // 1536 blocks = 8 XCD * 192
    const int u = (gid & 7) * 192 + (gid >> 3);
    const int mt = u % 6;                       // 6 consecutive share B-panel on one XCD
    const int bn = u / 6;
    const int b = bn >> 4;
    const int nt = bn & 15;
    const int t = threadIdx.x;
    const int lane = t & 63, w = t >> 6;
    const int l15 = lane & 15, quad = lane >> 4;

    f32x4 acc[2][2][4][2] = {};
    gemm256_core(smem, A + (size_t)(mt * 256) * CD,
                 Bt + ((size_t)b * NN + nt * 256) * CD, acc);

    const int sec = mt >> 1;                    // 0=Q 1=K 2=V
    const int lrb = mt * 256 - sec * 512;
#pragma unroll
    for (int qm = 0; qm < 2; ++qm)
#pragma unroll
    for (int mi = 0; mi < 4; ++mi) {
        const int ml = qm * 128 + (w >> 2) * 64 + mi * 16 + quad * 4;
#pragma unroll
        for (int qn = 0; qn < 2; ++qn)
#pragma unroll
        for (int ni = 0; ni < 2; ++ni) {
            const int n = nt * 256 + qn * 128 + (w & 3) * 32 + ni * 16 + l15;
            f32x4 v = acc[qm][qn][mi][ni];
            if (sec == 0) {
                ushort4 pk;
                pk.x = f2bf(v[0]); pk.y = f2bf(v[1]);
                pk.z = f2bf(v[2]); pk.w = f2bf(v[3]);
                *(ushort4*)&qt[((size_t)b * NN + n) * CD + mt * 256 + ml] = pk;
            } else {
                u16* dst = (sec == 1) ? kbuf : vbuf;
#pragma unroll
                for (int r = 0; r < 4; ++r)
                    dst[((size_t)(b * 512 + lrb + ml + r)) * NN + n] = f2bf(v[r]);
            }
        }
    }
}

// -------- fused exp + context: ctxT[bh][d][c] += sum_n exp(K[c][n]) V[d][n] ---
// 8 n-chunks (was 4): 1024 blocks -> 4 blocks/CU, latency-bound scattered
// V-reads hidden by TLP. Atomic count doubles; L2 absorbs.
__global__ __launch_bounds__(256) void k_ctx(const u16* __restrict__ kbuf,
                                             const u16* __restrict__ vbuf,
                                             float* __restrict__ ctxT,
                                             float* __restrict__ lsum) {
    const int bh = blockIdx.y;           // 0..127
    const int chunk = blockIdx.x;        // 0..7, 512 n each
    const int t = threadIdx.x, lane = t & 63, w = t >> 6;
    const int l15 = lane & 15, quad = lane >> 4;
    const int cb = w * 16;               // wave's 16 c-rows

    const u16* krow = kbuf + (size_t)(bh * 64 + cb + l15) * NN;
    const u16* vb   = vbuf + (size_t)bh * 64 * NN;

    f32x4 acc[4] = {};
    float ls = 0.f;
    for (int i = 0; i < 16; ++i) {
        int n0 = chunk * 512 + i * 32 + quad * 8;
        u16x8 ku = *(const u16x8*)&krow[n0];
        u16x8 afu;
#pragma unroll
        for (int jj = 0; jj < 8; ++jj) {
            float ev = __expf(fminf(bf2f(ku[jj]), 30.f));
            ls += ev;
            afu[jj] = f2bf(ev);
        }
        bf16x8 af = __builtin_bit_cast(bf16x8, afu);
#pragma unroll
        for (int di = 0; di < 4; ++di) {
            bf16x8 bfv = *(const bf16x8*)&vb[(size_t)(di * 16 + l15) * NN + n0];
            acc[di] = __builtin_amdgcn_mfma_f32_16x16x32_bf16(af, bfv, acc[di], 0, 0, 0);
        }
    }
    ls += __shfl_xor(ls, 16);
    ls += __shfl_xor(ls, 32);
    if (quad == 0) atomicAdd(&lsum[(size_t)bh * 64 + cb + l15], ls);

    const int c = cb + quad * 4;
#pragma unroll
    for (int di = 0; di < 4; ++di) {
        int d = di * 16 + l15;
#pragma unroll
        for (int r = 0; r < 4; ++r)
            atomicAdd(&ctxT[((size_t)bh * 64 + d) * 64 + c + r], acc[di][r]);
    }
}

// W_eff[b][o][h*64+c] = (1/l_c) * sum_d wout[o][h*64+d]*ctxT[b][h][d][c]
__global__ __launch_bounds__(256) void k_weff(const float* __restrict__ wout,
                                              const float* __restrict__ ctxT,
                                              const float* __restrict__ lsum,
                                              u16* __restrict__ weff) {
    int idx = blockIdx.x * 256 + threadIdx.x;   // 16*512*512
    int b = idx >> 18;
    int o = (idx >> 9) & 511;
    int hc = idx & 511;
    int h = hc >> 6, c = hc & 63;
    const float* wr = wout + o * 512 + h * 64;
    const float* cr = ctxT + ((size_t)b * 8 + h) * 4096 + c;
    float s = 0.f;
#pragma unroll
    for (int d = 0; d < 64; ++d) s += wr[d] * cr[d * 64];
    s *= 1.0f / lsum[((size_t)b * 8 + h) * 64 + c];
    weff[idx] = f2bf(s);
}

// ---------------- GEMM2: Y_b = W_eff_b(512x512) @ Q_b + b_out -----------------
__global__ __launch_bounds__(512, 4) void k_gemm2(
        const u16* __restrict__ weff, const u16* __restrict__ qt,
        const float* __restrict__ bout, float* __restrict__ y) {
    __shared__ __align__(16) u16 smem[32768];   // 64 KiB
    const int gid = blockIdx.x;                 // 512 blocks = 8 XCD * 64
    const int u = (gid & 7) * 64 + (gid >> 3);
    const int mt = u & 1;
    const int bn = u >> 1;
    const int b = bn >> 4;
    const int nt = bn & 15;
    const int t = threadIdx.x;
    const int lane = t & 63, w = t >> 6;
    const int l15 = lane & 15, quad = lane >> 4;

    f32x4 acc[2][2][4][2] = {};
    gemm256_core(smem, weff + (size_t)b * 512 * 512 + (size_t)(mt * 256) * CD,
                 qt + ((size_t)b * NN + nt * 256) * CD, acc);

#pragma unroll
    for (int qm = 0; qm < 2; ++qm)
#pragma unroll
    for (int mi = 0; mi < 4; ++mi) {
        const int o = mt * 256 + qm * 128 + (w >> 2) * 64 + mi * 16 + quad * 4;
#pragma unroll
        for (int qn = 0; qn < 2; ++qn)
#pragma unroll
        for (int ni = 0; ni < 2; ++ni) {
            const int n = nt * 256 + qn * 128 + (w & 3) * 32 + ni * 16 + l15;
            f32x4 v = acc[qm][qn][mi][ni];
#pragma unroll
            for (int r = 0; r < 4; ++r)
                y[((size_t)(b * 512 + o + r)) * NN + n] = v[r] + bout[o + r];
        }
    }
}

extern "C" void kernel_launch(void* const* d_in, const int* in_sizes, int n_in,
                              void* d_out, int out_size, void* d_ws, size_t ws_size,
                              hipStream_t stream) {
    const float* x    = (const float*)d_in[0];
    const float* wqkv = (const float*)d_in[1];
    const float* wout = (const float*)d_in[2];
    const float* bout = (const float*)d_in[3];
    float* y = (float*)d_out;

    char* ws = (char*)d_ws;
    u16*   xt   = (u16*)(ws);                       //  67,108,864  xt[b][n][c] bf16
    u16*   wqb  = (u16*)(ws + 67108864);            //   1,572,864  wqkv bf16
    u16*   qt   = (u16*)(ws + 68681728);            //  67,108,864  Qt[b][n][c] bf16
    u16*   kbuf = (u16*)(ws + 135790592);           //  67,108,864  K raw [b*512][n]
    u16*   vbuf = (u16*)(ws + 202899456);           //  67,108,864  V [b*512][n]
    float* ctxT = (float*)(ws + 270008320);         //   2,097,152  contextT fp32 (unnorm)
    float* lsum = (float*)(ws + 272105472);         //      32,768  row sums
    u16*   weff = (u16*)(ws + 272138240);           //   8,388,608  W_eff bf16

    hipMemsetAsync(ctxT, 0, 2097152 + 32768, stream);  // ctxT + lsum contiguous

    k_convert<<<(O3 * CD + 255) / 256, 256, 0, stream>>>(wqkv, wqb, O3 * CD);
    k_transpose_x<<<dim3(64 * 8, NB), 256, 0, stream>>>(x, xt);
    k_gemm1<<<1536, 512, 0, stream>>>(wqb, xt, qt, kbuf, vbuf);
    k_ctx<<<dim3(8, NB * 8), 256, 0, stream>>>(kbuf, vbuf, ctxT, lsum);
    k_weff<<<(NB * 512 * 512) / 256, 256, 0, stream>>>(wout, ctxT, lsum, weff);
    k_gemm2<<<512, 512, 0, stream>>>(weff, qt, bout, y);
}